// Round 9
// baseline (258.471 us; speedup 1.0000x reference)
//
#include <hip/hip_runtime.h>

#define H 128
#define W 128
#define Zd 16
#define C 20
#define HWZ (H * W * Zd)
#define CHWZ (C * HWZ)
#define NXCD 8
#define CPGF 5       // channels per block (4 channel-groups)
#define NBLOCKS 512  // == exactly 2 blocks/CU x 256 CU co-resident

typedef float f4 __attribute__((ext_vector_type(4)));

__device__ __forceinline__ f4 load4(const float* p) { return *(const f4*)p; }
__device__ __forceinline__ f4 load4u(const float* p) {
    f4 r;
    __builtin_memcpy(&r, p, 16);
    return r;
}

// Device-scope grid barrier. ctr is zeroed by an async memset before launch,
// so arrivals this launch are exactly 1..NBLOCKS. Bounded spin: if co-residency
// ever failed we produce a wrong answer instead of a hang.
__device__ __forceinline__ void grid_barrier(unsigned long long* ctr) {
    __threadfence();   // release: publish this block's ws writes device-wide
    __syncthreads();
    if (threadIdx.x == 0) {
        __hip_atomic_fetch_add(ctr, 1ULL, __ATOMIC_ACQ_REL, __HIP_MEMORY_SCOPE_AGENT);
        long long spins = 0;
        while (__hip_atomic_load(ctr, __ATOMIC_ACQUIRE, __HIP_MEMORY_SCOPE_AGENT) <
               (unsigned long long)NBLOCKS) {
            if (++spins > (1LL << 28)) break;
        }
    }
    __syncthreads();
    __threadfence();   // acquire: see other blocks' ws writes
}

// Single kernel: grid = 512 blocks = xcd(8) x cgf(4) x row(16); XCD x owns
// rows [16x,16x+16). Block = one h-row x 5 channels; 512 threads cover (w,z4).
// Phase X: blur->ws (global). grid_barrier. Phase Y: ws->LDS. Phase Z: LDS->out.
__global__ __launch_bounds__(512, 4) void prop_all(const float* __restrict__ gd,
                                                   const float* __restrict__ blur,
                                                   float* __restrict__ ws,
                                                   float* __restrict__ out,
                                                   unsigned long long* __restrict__ bar) {
    const int bid = blockIdx.x;
    const int xcd = bid & (NXCD - 1);
    const int i = bid >> 3;     // 0..63
    const int cgf = i >> 4;     // 0..3
    const int h = (xcd << 4) + (i & 15);

    const int t = threadIdx.x;  // 0..511
    const int z4 = (t & 3) << 2;
    const int w = t >> 2;       // 0..127

    __shared__ float yout[CPGF][W][Zd];   // 40 KB

    const int DI[8] = {1, 1, 1, 0, 0, -1, -1, -1};
    const int DJ[8] = {1, 0, -1, 1, -1, 1, 0, -1};
    const int base = (h * W + w) * Zd + z4;
    const int loo = (z4 == 0) ? 0 : -1;
    const int hio = (z4 == 12) ? 3 : 4;

    // ======== Phase X (gates 0..7, taps shift in (h,w), z fixed) ========
    {
        f4 g[8];
        int noff[8];
        f4 A = {0, 0, 0, 0}, S = {0, 0, 0, 0};
#pragma unroll
        for (int k = 0; k < 8; ++k) {
            int hh = h + DI[k], ww = w + DJ[k];
            bool valid = ((unsigned)hh < H) && ((unsigned)ww < W);
            f4 val = {0, 0, 0, 0};
            if (valid) val = load4(gd + ((k * H + hh) * W + ww) * Zd + z4);
            g[k] = val;
            noff[k] = valid ? (DI[k] * W + DJ[k]) * Zd : 0;
#pragma unroll
            for (int e = 0; e < 4; ++e) A[e] += __builtin_fabsf(val[e]);
            S += val;
        }
        f4 invA = 1.0f / A;
        f4 c0 = 1.0f - S * invA;
#pragma unroll
        for (int k = 0; k < 8; ++k) g[k] *= invA;

#pragma unroll
        for (int cc = 0; cc < CPGF; ++cc) {
            const int c = cgf * CPGF + cc;
            const float* pc = blur + c * HWZ + base;
            f4 acc = c0 * load4(pc);
#pragma unroll
            for (int k = 0; k < 8; ++k) acc += g[k] * load4(pc + noff[k]);
            *(f4*)(ws + c * HWZ + base) = acc;
        }
    }

    grid_barrier(bar);

    // ======== Phase Y (gates 8..15, row = h, row stride W*Zd) ========
    {
        const int gbase = (((8 * H) + h) * W + w) * Zd + z4;
        f4 g[8];
        f4 A = {0, 0, 0, 0}, S = {0, 0, 0, 0};
#pragma unroll
        for (int k = 0; k < 8; ++k) {
            int di = DI[k], dj = DJ[k];
            bool rv = (unsigned)(h + di) < H;
            f4 val = {0, 0, 0, 0};
            if (rv) {
                val = (dj == 0) ? load4(gd + gbase + k * HWZ + di * (W * Zd))
                                : load4u(gd + gbase + k * HWZ + di * (W * Zd) + dj);
                if (dj == -1 && z4 == 0) val[0] = 0.f;
                if (dj == 1 && z4 == 12) val[3] = 0.f;
            }
            g[k] = val;
#pragma unroll
            for (int e = 0; e < 4; ++e) A[e] += __builtin_fabsf(val[e]);
            S += val;
        }
        f4 invA = 1.0f / A;
        f4 c0 = 1.0f - S * invA;
#pragma unroll
        for (int k = 0; k < 8; ++k) g[k] *= invA;

        f4 gp[3] = {g[0], g[3], g[5]};
        f4 gc[3] = {g[1], c0, g[6]};
        f4 gm[3] = {g[2], g[4], g[7]};
        const int DIr[3] = {1, 0, -1};
        int rowoff[3];
#pragma unroll
        for (int r = 0; r < 3; ++r)
            rowoff[r] = ((unsigned)(h + DIr[r]) < H) ? DIr[r] * (W * Zd) : 0;

#pragma unroll
        for (int cc = 0; cc < CPGF; ++cc) {
            const int c = cgf * CPGF + cc;
            const float* pc = ws + c * HWZ + base;
            f4 acc = {0, 0, 0, 0};
#pragma unroll
            for (int r = 0; r < 3; ++r) {
                const float* pr = pc + rowoff[r];
                f4 v = load4(pr);
                float lo = pr[loo];
                float hi = pr[hio];
                f4 tm = {lo, v[0], v[1], v[2]};
                f4 tp = {v[1], v[2], v[3], hi};
                acc += gm[r] * tm + gc[r] * v + gp[r] * tp;
            }
            *(f4*)(&yout[cc][w][z4]) = acc;
        }
    }

    __syncthreads();

    // ======== Phase Z (gates 16..23, row = w, row stride Zd, from LDS) ========
    {
        const int gbase = (((16 * H) + h) * W + w) * Zd + z4;
        f4 g[8];
        f4 A = {0, 0, 0, 0}, S = {0, 0, 0, 0};
#pragma unroll
        for (int k = 0; k < 8; ++k) {
            int di = DI[k], dj = DJ[k];
            bool rv = (unsigned)(w + di) < W;
            f4 val = {0, 0, 0, 0};
            if (rv) {
                val = (dj == 0) ? load4(gd + gbase + k * HWZ + di * Zd)
                                : load4u(gd + gbase + k * HWZ + di * Zd + dj);
                if (dj == -1 && z4 == 0) val[0] = 0.f;
                if (dj == 1 && z4 == 12) val[3] = 0.f;
            }
            g[k] = val;
#pragma unroll
            for (int e = 0; e < 4; ++e) A[e] += __builtin_fabsf(val[e]);
            S += val;
        }
        f4 invA = 1.0f / A;
        f4 c0 = 1.0f - S * invA;
#pragma unroll
        for (int k = 0; k < 8; ++k) g[k] *= invA;

        f4 gp[3] = {g[0], g[3], g[5]};
        f4 gc[3] = {g[1], c0, g[6]};
        f4 gm[3] = {g[2], g[4], g[7]};
        const int DIr[3] = {1, 0, -1};
        int woff[3];  // LDS float offset for row w+di
#pragma unroll
        for (int r = 0; r < 3; ++r)
            woff[r] = ((unsigned)(w + DIr[r]) < W) ? DIr[r] * Zd : 0;

#pragma unroll
        for (int cc = 0; cc < CPGF; ++cc) {
            const int c = cgf * CPGF + cc;
            const float* pl = &yout[cc][w][z4];
            f4 acc = {0, 0, 0, 0};
#pragma unroll
            for (int r = 0; r < 3; ++r) {
                const float* pr = pl + woff[r];
                f4 v = load4(pr);
                float lo = pr[loo];
                float hi = pr[hio];
                f4 tm = {lo, v[0], v[1], v[2]};
                f4 tp = {v[1], v[2], v[3], hi};
                acc += gm[r] * tm + gc[r] * v + gp[r] * tp;
            }
            *(f4*)(out + c * HWZ + base) = acc;
        }
    }
}

extern "C" void kernel_launch(void* const* d_in, const int* in_sizes, int n_in,
                              void* d_out, int out_size, void* d_ws, size_t ws_size,
                              hipStream_t stream) {
    const float* gd = (const float*)d_in[0];   // guidance (24,128,128,16) f32
    const float* blur = (const float*)d_in[1]; // blur (20,128,128,16) f32
    float* out = (float*)d_out;                // (20,128,128,16) f32
    float* ws = (float*)d_ws;                  // [0, 21MB): X-out; +21MB: barrier
    unsigned long long* bar = (unsigned long long*)((char*)d_ws + (size_t)CHWZ * 4);

    hipMemsetAsync(bar, 0, 8, stream);  // zero the barrier counter (graph-capturable)
    prop_all<<<dim3(NBLOCKS), dim3(512), 0, stream>>>(gd, blur, ws, out, bar);
}

// Round 10
// 243.240 us; speedup vs baseline: 1.0626x; 1.0626x over previous
//
#include <hip/hip_runtime.h>

#define H 128
#define W 128
#define Zd 16
#define C 20
#define HWZ (H * W * Zd)
#define CHWZ (C * HWZ)
#define NXCD 8
#define CPGF 5       // channels per block (4 channel-groups)
#define NBLOCKS 512  // fits co-resident (4 blocks/CU by LDS, 256 CUs)

typedef float f4 __attribute__((ext_vector_type(4)));

__device__ __forceinline__ f4 load4(const float* p) { return *(const f4*)p; }
__device__ __forceinline__ f4 load4u(const float* p) {
    f4 r;
    __builtin_memcpy(&r, p, 16);
    return r;
}

// Device-scope grid barrier. ctr zeroed by async memset before launch.
// KEY: spin on RELAXED loads (acquire-loads invalidate caches per-poll on
// CDNA -> chip-wide thrash, R9 regression). Acquire ordering is supplied once
// after the spin by __syncthreads()+__threadfence(). s_sleep cuts poll traffic.
__device__ __forceinline__ void grid_barrier(unsigned long long* ctr) {
    __threadfence();   // release: publish this block's ws writes device-wide
    __syncthreads();
    if (threadIdx.x == 0) {
        __hip_atomic_fetch_add(ctr, 1ULL, __ATOMIC_ACQ_REL, __HIP_MEMORY_SCOPE_AGENT);
        long long spins = 0;
        while (__hip_atomic_load(ctr, __ATOMIC_RELAXED, __HIP_MEMORY_SCOPE_AGENT) <
               (unsigned long long)NBLOCKS) {
            __builtin_amdgcn_s_sleep(8);   // ~512 cycles between polls
            if (++spins > (1LL << 20)) break;  // bounded: fail loud, not hung
        }
    }
    __syncthreads();
    __threadfence();   // acquire side: discard stale lines before reading ws
}

// Single kernel: grid = 512 blocks = xcd(8) x cgf(4) x row(16); XCD x owns
// rows [16x,16x+16). Block = one h-row x 5 channels; 512 threads cover (w,z4).
// Phase X: blur->ws (global). grid_barrier. Phase Y: ws->LDS. Phase Z: LDS->out.
__global__ __launch_bounds__(512, 4) void prop_all(const float* __restrict__ gd,
                                                   const float* __restrict__ blur,
                                                   float* __restrict__ ws,
                                                   float* __restrict__ out,
                                                   unsigned long long* __restrict__ bar) {
    const int bid = blockIdx.x;
    const int xcd = bid & (NXCD - 1);
    const int i = bid >> 3;     // 0..63
    const int cgf = i >> 4;     // 0..3
    const int h = (xcd << 4) + (i & 15);

    const int t = threadIdx.x;  // 0..511
    const int z4 = (t & 3) << 2;
    const int w = t >> 2;       // 0..127

    __shared__ float yout[CPGF][W][Zd];   // 40 KB

    const int DI[8] = {1, 1, 1, 0, 0, -1, -1, -1};
    const int DJ[8] = {1, 0, -1, 1, -1, 1, 0, -1};
    const int base = (h * W + w) * Zd + z4;
    const int loo = (z4 == 0) ? 0 : -1;
    const int hio = (z4 == 12) ? 3 : 4;

    // ======== Phase X (gates 0..7, taps shift in (h,w), z fixed) ========
    {
        f4 g[8];
        int noff[8];
        f4 A = {0, 0, 0, 0}, S = {0, 0, 0, 0};
#pragma unroll
        for (int k = 0; k < 8; ++k) {
            int hh = h + DI[k], ww = w + DJ[k];
            bool valid = ((unsigned)hh < H) && ((unsigned)ww < W);
            f4 val = {0, 0, 0, 0};
            if (valid) val = load4(gd + ((k * H + hh) * W + ww) * Zd + z4);
            g[k] = val;
            noff[k] = valid ? (DI[k] * W + DJ[k]) * Zd : 0;
#pragma unroll
            for (int e = 0; e < 4; ++e) A[e] += __builtin_fabsf(val[e]);
            S += val;
        }
        f4 invA = 1.0f / A;
        f4 c0 = 1.0f - S * invA;
#pragma unroll
        for (int k = 0; k < 8; ++k) g[k] *= invA;

#pragma unroll
        for (int cc = 0; cc < CPGF; ++cc) {
            const int c = cgf * CPGF + cc;
            const float* pc = blur + c * HWZ + base;
            f4 acc = c0 * load4(pc);
#pragma unroll
            for (int k = 0; k < 8; ++k) acc += g[k] * load4(pc + noff[k]);
            *(f4*)(ws + c * HWZ + base) = acc;
        }
    }

    grid_barrier(bar);

    // ======== Phase Y (gates 8..15, row = h, row stride W*Zd) ========
    {
        const int gbase = (((8 * H) + h) * W + w) * Zd + z4;
        f4 g[8];
        f4 A = {0, 0, 0, 0}, S = {0, 0, 0, 0};
#pragma unroll
        for (int k = 0; k < 8; ++k) {
            int di = DI[k], dj = DJ[k];
            bool rv = (unsigned)(h + di) < H;
            f4 val = {0, 0, 0, 0};
            if (rv) {
                val = (dj == 0) ? load4(gd + gbase + k * HWZ + di * (W * Zd))
                                : load4u(gd + gbase + k * HWZ + di * (W * Zd) + dj);
                if (dj == -1 && z4 == 0) val[0] = 0.f;
                if (dj == 1 && z4 == 12) val[3] = 0.f;
            }
            g[k] = val;
#pragma unroll
            for (int e = 0; e < 4; ++e) A[e] += __builtin_fabsf(val[e]);
            S += val;
        }
        f4 invA = 1.0f / A;
        f4 c0 = 1.0f - S * invA;
#pragma unroll
        for (int k = 0; k < 8; ++k) g[k] *= invA;

        f4 gp[3] = {g[0], g[3], g[5]};
        f4 gc[3] = {g[1], c0, g[6]};
        f4 gm[3] = {g[2], g[4], g[7]};
        const int DIr[3] = {1, 0, -1};
        int rowoff[3];
#pragma unroll
        for (int r = 0; r < 3; ++r)
            rowoff[r] = ((unsigned)(h + DIr[r]) < H) ? DIr[r] * (W * Zd) : 0;

#pragma unroll
        for (int cc = 0; cc < CPGF; ++cc) {
            const int c = cgf * CPGF + cc;
            const float* pc = ws + c * HWZ + base;
            f4 acc = {0, 0, 0, 0};
#pragma unroll
            for (int r = 0; r < 3; ++r) {
                const float* pr = pc + rowoff[r];
                f4 v = load4(pr);
                float lo = pr[loo];
                float hi = pr[hio];
                f4 tm = {lo, v[0], v[1], v[2]};
                f4 tp = {v[1], v[2], v[3], hi};
                acc += gm[r] * tm + gc[r] * v + gp[r] * tp;
            }
            *(f4*)(&yout[cc][w][z4]) = acc;
        }
    }

    __syncthreads();

    // ======== Phase Z (gates 16..23, row = w, row stride Zd, from LDS) ========
    {
        const int gbase = (((16 * H) + h) * W + w) * Zd + z4;
        f4 g[8];
        f4 A = {0, 0, 0, 0}, S = {0, 0, 0, 0};
#pragma unroll
        for (int k = 0; k < 8; ++k) {
            int di = DI[k], dj = DJ[k];
            bool rv = (unsigned)(w + di) < W;
            f4 val = {0, 0, 0, 0};
            if (rv) {
                val = (dj == 0) ? load4(gd + gbase + k * HWZ + di * Zd)
                                : load4u(gd + gbase + k * HWZ + di * Zd + dj);
                if (dj == -1 && z4 == 0) val[0] = 0.f;
                if (dj == 1 && z4 == 12) val[3] = 0.f;
            }
            g[k] = val;
#pragma unroll
            for (int e = 0; e < 4; ++e) A[e] += __builtin_fabsf(val[e]);
            S += val;
        }
        f4 invA = 1.0f / A;
        f4 c0 = 1.0f - S * invA;
#pragma unroll
        for (int k = 0; k < 8; ++k) g[k] *= invA;

        f4 gp[3] = {g[0], g[3], g[5]};
        f4 gc[3] = {g[1], c0, g[6]};
        f4 gm[3] = {g[2], g[4], g[7]};
        const int DIr[3] = {1, 0, -1};
        int woff[3];  // LDS float offset for row w+di
#pragma unroll
        for (int r = 0; r < 3; ++r)
            woff[r] = ((unsigned)(w + DIr[r]) < W) ? DIr[r] * Zd : 0;

#pragma unroll
        for (int cc = 0; cc < CPGF; ++cc) {
            const int c = cgf * CPGF + cc;
            const float* pl = &yout[cc][w][z4];
            f4 acc = {0, 0, 0, 0};
#pragma unroll
            for (int r = 0; r < 3; ++r) {
                const float* pr = pl + woff[r];
                f4 v = load4(pr);
                float lo = pr[loo];
                float hi = pr[hio];
                f4 tm = {lo, v[0], v[1], v[2]};
                f4 tp = {v[1], v[2], v[3], hi};
                acc += gm[r] * tm + gc[r] * v + gp[r] * tp;
            }
            *(f4*)(out + c * HWZ + base) = acc;
        }
    }
}

extern "C" void kernel_launch(void* const* d_in, const int* in_sizes, int n_in,
                              void* d_out, int out_size, void* d_ws, size_t ws_size,
                              hipStream_t stream) {
    const float* gd = (const float*)d_in[0];   // guidance (24,128,128,16) f32
    const float* blur = (const float*)d_in[1]; // blur (20,128,128,16) f32
    float* out = (float*)d_out;                // (20,128,128,16) f32
    float* ws = (float*)d_ws;                  // [0, 21MB): X-out; +21MB: barrier
    unsigned long long* bar = (unsigned long long*)((char*)d_ws + (size_t)CHWZ * 4);

    hipMemsetAsync(bar, 0, 8, stream);  // zero the barrier counter (graph-capturable)
    prop_all<<<dim3(NBLOCKS), dim3(512), 0, stream>>>(gd, blur, ws, out, bar);
}

// Round 11
// 29.057 us; speedup vs baseline: 8.8953x; 8.3712x over previous
//
#include <hip/hip_runtime.h>

#define H 128
#define W 128
#define Zd 16
#define C 20
#define HWZ (H * W * Zd)   // 262144 spatial positions

#define CG 5               // channel groups for prop_x
#define CPG (C / CG)       // 4 channels per thread
#define POSBLOCKS 256
#define NXCD 8
#define CPGF 5             // channels per block in yz (4 channel-groups)

typedef float f4 __attribute__((ext_vector_type(4)));

__device__ __forceinline__ f4 load4(const float* p) { return *(const f4*)p; }
__device__ __forceinline__ f4 load4u(const float* p) {
    f4 r;
    __builtin_memcpy(&r, p, 16);
    return r;
}

// DPP lane shifts (row-local, 16-lane rows). Boundary lanes get 0 (old value).
// Safe here: any lane where the shifted value is garbage has zi==0/3, i.e.
// z4==0/12, whose gate coefficient is explicitly zeroed.
__device__ __forceinline__ float dpp_prev(float x) {  // lane i <- lane i-1 (row_shr:1)
    int r = __builtin_amdgcn_update_dpp(0, __builtin_bit_cast(int, x), 0x111, 0xF, 0xF, false);
    return __builtin_bit_cast(float, r);
}
__device__ __forceinline__ float dpp_next(float x) {  // lane i <- lane i+1 (row_shl:1)
    int r = __builtin_amdgcn_update_dpp(0, __builtin_bit_cast(int, x), 0x101, 0xF, 0xF, false);
    return __builtin_bit_cast(float, r);
}

// XCD-aware decode for prop_x: XCD x owns h-slab [16x,16x+16) for all 5 cgroups.
__device__ __forceinline__ void decode(int bid, int tidx, int& cg, int& tid) {
    int xcd = bid & (NXCD - 1);
    int i = bid >> 3;          // 0..159
    cg = i >> 5;               // 0..4
    int pb = (xcd << 5) + (i & 31);
    tid = pb * 256 + tidx;
}

// ---------------- X step (R5 version, unchanged): taps shift in (h,w), z fixed
__global__ __launch_bounds__(256) void prop_x(const float* __restrict__ gd,
                                              const float* __restrict__ in,
                                              float* __restrict__ out) {
    int cg, tid;
    decode(blockIdx.x, threadIdx.x, cg, tid);
    const int z4 = (tid & 3) << 2;
    const int w = (tid >> 2) & (W - 1);
    const int h = tid >> 9;

    const int DI[8] = {1, 1, 1, 0, 0, -1, -1, -1};
    const int DJ[8] = {1, 0, -1, 1, -1, 1, 0, -1};

    f4 g[8];
    int noff[8];
    f4 A = {0, 0, 0, 0}, S = {0, 0, 0, 0};
#pragma unroll
    for (int k = 0; k < 8; ++k) {
        int hh = h + DI[k], ww = w + DJ[k];
        bool valid = ((unsigned)hh < H) && ((unsigned)ww < W);
        f4 val = {0, 0, 0, 0};
        if (valid) val = load4(gd + ((k * H + hh) * W + ww) * Zd + z4);
        g[k] = val;
        noff[k] = valid ? (DI[k] * W + DJ[k]) * Zd : 0;
#pragma unroll
        for (int e = 0; e < 4; ++e) A[e] += __builtin_fabsf(val[e]);
        S += val;
    }
    f4 invA = 1.0f / A;
    f4 c0 = 1.0f - S * invA;
#pragma unroll
    for (int k = 0; k < 8; ++k) g[k] *= invA;

    const int base = (h * W + w) * Zd + z4;
#pragma unroll
    for (int cc = 0; cc < CPG; ++cc) {
        const int c = cg * CPG + cc;
        const float* pc = in + c * HWZ + base;
        f4 acc = c0 * load4(pc);
#pragma unroll
        for (int k = 0; k < 8; ++k) acc += g[k] * load4(pc + noff[k]);
        *(f4*)(out + c * HWZ + base) = acc;
    }
}

// ---------------- Fused Y+Z with DPP z-shifts: one block = one h-row x 5 ch.
// All z+-1 accesses (gate planes and taps) built from aligned f4 loads + DPP
// lane shifts instead of extra/unaligned memory ops.
__global__ __launch_bounds__(512) void prop_yz(const float* __restrict__ gd,
                                               const float* __restrict__ in,
                                               float* __restrict__ out) {
    // grid = 512 blocks: xcd(8) x cgf(4) x row(16); XCD x owns rows [16x,16x+16)
    const int bid = blockIdx.x;
    const int xcd = bid & (NXCD - 1);
    const int i = bid >> 3;     // 0..63
    const int cgf = i >> 4;     // 0..3
    const int h = (xcd << 4) + (i & 15);

    const int t = threadIdx.x;  // 0..511
    const int z4 = (t & 3) << 2;
    const int w = t >> 2;       // 0..127

    __shared__ float yout[CPGF][W][Zd];   // 40 KB

    const int DI[8] = {1, 1, 1, 0, 0, -1, -1, -1};
    const int DJ[8] = {1, 0, -1, 1, -1, 1, 0, -1};
    const int base = (h * W + w) * Zd + z4;

    // ======== Y step (gates 8..15, row = h, row stride W*Zd) ========
    {
        const int gbase = (((8 * H) + h) * W + w) * Zd + z4;
        f4 g[8];
        f4 A = {0, 0, 0, 0}, S = {0, 0, 0, 0};
#pragma unroll
        for (int k = 0; k < 8; ++k) {
            int di = DI[k], dj = DJ[k];
            bool rv = (unsigned)(h + di) < H;
            f4 va = {0, 0, 0, 0};
            if (rv) va = load4(gd + gbase + k * HWZ + di * (W * Zd));
            f4 val;
            if (dj == 0) {
                val = va;
            } else if (dj == -1) {
                val = (f4){dpp_prev(va[3]), va[0], va[1], va[2]};
                if (z4 == 0) val[0] = 0.f;
            } else {
                val = (f4){va[1], va[2], va[3], dpp_next(va[0])};
                if (z4 == 12) val[3] = 0.f;
            }
            g[k] = val;
#pragma unroll
            for (int e = 0; e < 4; ++e) A[e] += __builtin_fabsf(val[e]);
            S += val;
        }
        f4 invA = 1.0f / A;
        f4 c0 = 1.0f - S * invA;
#pragma unroll
        for (int k = 0; k < 8; ++k) g[k] *= invA;

        f4 gp[3] = {g[0], g[3], g[5]};   // dj=+1 per row {di=+1,0,-1}
        f4 gc[3] = {g[1], c0, g[6]};
        f4 gm[3] = {g[2], g[4], g[7]};
        const int DIr[3] = {1, 0, -1};
        int rowoff[3];
#pragma unroll
        for (int r = 0; r < 3; ++r)
            rowoff[r] = ((unsigned)(h + DIr[r]) < H) ? DIr[r] * (W * Zd) : 0;

#pragma unroll
        for (int cc = 0; cc < CPGF; ++cc) {
            const int c = cgf * CPGF + cc;
            const float* pc = in + c * HWZ + base;
            f4 acc = {0, 0, 0, 0};
#pragma unroll
            for (int r = 0; r < 3; ++r) {
                f4 v = load4(pc + rowoff[r]);
                float lo = dpp_prev(v[3]);
                float hi = dpp_next(v[0]);
                acc += gm[r] * (f4){lo, v[0], v[1], v[2]} + gc[r] * v +
                       gp[r] * (f4){v[1], v[2], v[3], hi};
            }
            *(f4*)(&yout[cc][w][z4]) = acc;
        }
    }

    __syncthreads();

    // ======== Z step (gates 16..23, row = w, row stride Zd, taps from LDS) ========
    {
        const int gbase = (((16 * H) + h) * W + w) * Zd + z4;
        f4 g[8];
        f4 A = {0, 0, 0, 0}, S = {0, 0, 0, 0};
#pragma unroll
        for (int k = 0; k < 8; ++k) {
            int di = DI[k], dj = DJ[k];
            bool rv = (unsigned)(w + di) < W;
            f4 va = {0, 0, 0, 0};
            if (rv) va = load4(gd + gbase + k * HWZ + di * Zd);
            f4 val;
            if (dj == 0) {
                val = va;
            } else if (dj == -1) {
                val = (f4){dpp_prev(va[3]), va[0], va[1], va[2]};
                if (z4 == 0) val[0] = 0.f;
            } else {
                val = (f4){va[1], va[2], va[3], dpp_next(va[0])};
                if (z4 == 12) val[3] = 0.f;
            }
            g[k] = val;
#pragma unroll
            for (int e = 0; e < 4; ++e) A[e] += __builtin_fabsf(val[e]);
            S += val;
        }
        f4 invA = 1.0f / A;
        f4 c0 = 1.0f - S * invA;
#pragma unroll
        for (int k = 0; k < 8; ++k) g[k] *= invA;

        f4 gp[3] = {g[0], g[3], g[5]};
        f4 gc[3] = {g[1], c0, g[6]};
        f4 gm[3] = {g[2], g[4], g[7]};
        const int DIr[3] = {1, 0, -1};
        int woff[3];  // LDS float offset for row w+di
#pragma unroll
        for (int r = 0; r < 3; ++r)
            woff[r] = ((unsigned)(w + DIr[r]) < W) ? DIr[r] * Zd : 0;

#pragma unroll
        for (int cc = 0; cc < CPGF; ++cc) {
            const int c = cgf * CPGF + cc;
            const float* pl = &yout[cc][w][z4];
            f4 acc = {0, 0, 0, 0};
#pragma unroll
            for (int r = 0; r < 3; ++r) {
                f4 v = load4(pl + woff[r]);
                float lo = dpp_prev(v[3]);
                float hi = dpp_next(v[0]);
                acc += gm[r] * (f4){lo, v[0], v[1], v[2]} + gc[r] * v +
                       gp[r] * (f4){v[1], v[2], v[3], hi};
            }
            *(f4*)(out + c * HWZ + base) = acc;
        }
    }
}

extern "C" void kernel_launch(void* const* d_in, const int* in_sizes, int n_in,
                              void* d_out, int out_size, void* d_ws, size_t ws_size,
                              hipStream_t stream) {
    const float* gd = (const float*)d_in[0];   // guidance (24,128,128,16) f32
    const float* blur = (const float*)d_in[1]; // blur (20,128,128,16) f32
    float* out = (float*)d_out;                // (20,128,128,16) f32
    float* ws = (float*)d_ws;

    prop_x<<<dim3(POSBLOCKS * CG), dim3(256), 0, stream>>>(gd, blur, ws); // X: blur -> ws
    prop_yz<<<dim3(512), dim3(512), 0, stream>>>(gd, ws, out);            // Y+Z: ws -> out
}

// Round 12
// 28.180 us; speedup vs baseline: 9.1722x; 1.0311x over previous
//
#include <hip/hip_runtime.h>

#define H 128
#define W 128
#define Zd 16
#define C 20
#define HWZ (H * W * Zd)   // 262144 spatial positions

#define CG 4               // channel groups for prop_x (5 ch/thread)
#define NXCD 8
#define CPGF2 10           // channels per block in yz (2 channel-groups)

typedef float f4 __attribute__((ext_vector_type(4)));

__device__ __forceinline__ f4 load4(const float* p) { return *(const f4*)p; }

// DPP lane shifts (16-lane rows). Boundary lanes get 0; safe because any lane
// where the shifted value is garbage has z4==0/12 and its gate coeff is zeroed.
__device__ __forceinline__ float dpp_prev(float x) {  // lane i <- lane i-1
    int r = __builtin_amdgcn_update_dpp(0, __builtin_bit_cast(int, x), 0x111, 0xF, 0xF, false);
    return __builtin_bit_cast(float, r);
}
__device__ __forceinline__ float dpp_next(float x) {  // lane i <- lane i+1
    int r = __builtin_amdgcn_update_dpp(0, __builtin_bit_cast(int, x), 0x101, 0xF, 0xF, false);
    return __builtin_bit_cast(float, r);
}

// ---------------- X step: taps shift in (h,w), z fixed. CG=4 channel groups.
// grid = 1024 blocks: xcd=bid&7 owns rows [16x,16x+16) for all 4 cgroups.
__global__ __launch_bounds__(256) void prop_x(const float* __restrict__ gd,
                                              const float* __restrict__ in,
                                              float* __restrict__ out) {
    const int bid = blockIdx.x;
    const int xcd = bid & (NXCD - 1);
    const int i = bid >> 3;          // 0..127
    const int cg = i >> 5;           // 0..3
    const int pb = (xcd << 5) + (i & 31);
    const int tid = pb * 256 + threadIdx.x;

    const int z4 = (tid & 3) << 2;
    const int w = (tid >> 2) & (W - 1);
    const int h = tid >> 9;

    const int DI[8] = {1, 1, 1, 0, 0, -1, -1, -1};
    const int DJ[8] = {1, 0, -1, 1, -1, 1, 0, -1};

    f4 g[8];
    int noff[8];
    f4 A = {0, 0, 0, 0}, S = {0, 0, 0, 0};
#pragma unroll
    for (int k = 0; k < 8; ++k) {
        int hh = h + DI[k], ww = w + DJ[k];
        bool valid = ((unsigned)hh < H) && ((unsigned)ww < W);
        f4 val = {0, 0, 0, 0};
        if (valid) val = load4(gd + ((k * H + hh) * W + ww) * Zd + z4);
        g[k] = val;
        noff[k] = valid ? (DI[k] * W + DJ[k]) * Zd : 0;
#pragma unroll
        for (int e = 0; e < 4; ++e) A[e] += __builtin_fabsf(val[e]);
        S += val;
    }
    f4 invA = 1.0f / A;
    f4 c0 = 1.0f - S * invA;
#pragma unroll
    for (int k = 0; k < 8; ++k) g[k] *= invA;

    const int base = (h * W + w) * Zd + z4;
#pragma unroll
    for (int cc = 0; cc < 5; ++cc) {
        const int c = cg * 5 + cc;
        const float* pc = in + c * HWZ + base;
        f4 acc = c0 * load4(pc);
#pragma unroll
        for (int k = 0; k < 8; ++k) acc += g[k] * load4(pc + noff[k]);
        *(f4*)(out + c * HWZ + base) = acc;
    }
}

// ---------------- Fused Y+Z with DPP z-shifts: one block = one h-row x 10 ch.
// yout in DYNAMIC LDS (80 KB f32). grid = 256: xcd(8) x cgf(2) x row(16).
__global__ __launch_bounds__(512) void prop_yz(const float* __restrict__ gd,
                                               const float* __restrict__ in,
                                               float* __restrict__ out) {
    extern __shared__ float yout[];   // [CPGF2][W][Zd] = 80 KB

    const int bid = blockIdx.x;
    const int xcd = bid & (NXCD - 1);
    const int i = bid >> 3;     // 0..31
    const int cgf = i >> 4;     // 0..1
    const int h = (xcd << 4) + (i & 15);

    const int t = threadIdx.x;  // 0..511
    const int z4 = (t & 3) << 2;
    const int w = t >> 2;       // 0..127

    const int DI[8] = {1, 1, 1, 0, 0, -1, -1, -1};
    const int DJ[8] = {1, 0, -1, 1, -1, 1, 0, -1};
    const int base = (h * W + w) * Zd + z4;

    // ======== Y step (gates 8..15, row = h, row stride W*Zd) ========
    {
        const int gbase = (((8 * H) + h) * W + w) * Zd + z4;
        f4 g[8];
        f4 A = {0, 0, 0, 0}, S = {0, 0, 0, 0};
#pragma unroll
        for (int k = 0; k < 8; ++k) {
            int di = DI[k], dj = DJ[k];
            bool rv = (unsigned)(h + di) < H;
            f4 va = {0, 0, 0, 0};
            if (rv) va = load4(gd + gbase + k * HWZ + di * (W * Zd));
            f4 val;
            if (dj == 0) {
                val = va;
            } else if (dj == -1) {
                val = (f4){dpp_prev(va[3]), va[0], va[1], va[2]};
                if (z4 == 0) val[0] = 0.f;
            } else {
                val = (f4){va[1], va[2], va[3], dpp_next(va[0])};
                if (z4 == 12) val[3] = 0.f;
            }
            g[k] = val;
#pragma unroll
            for (int e = 0; e < 4; ++e) A[e] += __builtin_fabsf(val[e]);
            S += val;
        }
        f4 invA = 1.0f / A;
        f4 c0 = 1.0f - S * invA;
#pragma unroll
        for (int k = 0; k < 8; ++k) g[k] *= invA;

        f4 gp[3] = {g[0], g[3], g[5]};   // dj=+1 per row {di=+1,0,-1}
        f4 gc[3] = {g[1], c0, g[6]};
        f4 gm[3] = {g[2], g[4], g[7]};
        const int DIr[3] = {1, 0, -1};
        int rowoff[3];
#pragma unroll
        for (int r = 0; r < 3; ++r)
            rowoff[r] = ((unsigned)(h + DIr[r]) < H) ? DIr[r] * (W * Zd) : 0;

#pragma unroll 2
        for (int cc = 0; cc < CPGF2; ++cc) {
            const int c = cgf * CPGF2 + cc;
            const float* pc = in + c * HWZ + base;
            f4 acc = {0, 0, 0, 0};
#pragma unroll
            for (int r = 0; r < 3; ++r) {
                f4 v = load4(pc + rowoff[r]);
                float lo = dpp_prev(v[3]);
                float hi = dpp_next(v[0]);
                acc += gm[r] * (f4){lo, v[0], v[1], v[2]} + gc[r] * v +
                       gp[r] * (f4){v[1], v[2], v[3], hi};
            }
            *(f4*)(&yout[(cc * W + w) * Zd + z4]) = acc;
        }
    }

    __syncthreads();

    // ======== Z step (gates 16..23, row = w, row stride Zd, taps from LDS) ========
    {
        const int gbase = (((16 * H) + h) * W + w) * Zd + z4;
        f4 g[8];
        f4 A = {0, 0, 0, 0}, S = {0, 0, 0, 0};
#pragma unroll
        for (int k = 0; k < 8; ++k) {
            int di = DI[k], dj = DJ[k];
            bool rv = (unsigned)(w + di) < W;
            f4 va = {0, 0, 0, 0};
            if (rv) va = load4(gd + gbase + k * HWZ + di * Zd);
            f4 val;
            if (dj == 0) {
                val = va;
            } else if (dj == -1) {
                val = (f4){dpp_prev(va[3]), va[0], va[1], va[2]};
                if (z4 == 0) val[0] = 0.f;
            } else {
                val = (f4){va[1], va[2], va[3], dpp_next(va[0])};
                if (z4 == 12) val[3] = 0.f;
            }
            g[k] = val;
#pragma unroll
            for (int e = 0; e < 4; ++e) A[e] += __builtin_fabsf(val[e]);
            S += val;
        }
        f4 invA = 1.0f / A;
        f4 c0 = 1.0f - S * invA;
#pragma unroll
        for (int k = 0; k < 8; ++k) g[k] *= invA;

        f4 gp[3] = {g[0], g[3], g[5]};
        f4 gc[3] = {g[1], c0, g[6]};
        f4 gm[3] = {g[2], g[4], g[7]};
        const int DIr[3] = {1, 0, -1};
        int woff[3];  // LDS float offset for row w+di
#pragma unroll
        for (int r = 0; r < 3; ++r)
            woff[r] = ((unsigned)(w + DIr[r]) < W) ? DIr[r] * Zd : 0;

#pragma unroll 2
        for (int cc = 0; cc < CPGF2; ++cc) {
            const int c = cgf * CPGF2 + cc;
            const float* pl = &yout[(cc * W + w) * Zd + z4];
            f4 acc = {0, 0, 0, 0};
#pragma unroll
            for (int r = 0; r < 3; ++r) {
                f4 v = load4(pl + woff[r]);
                float lo = dpp_prev(v[3]);
                float hi = dpp_next(v[0]);
                acc += gm[r] * (f4){lo, v[0], v[1], v[2]} + gc[r] * v +
                       gp[r] * (f4){v[1], v[2], v[3], hi};
            }
            *(f4*)(out + c * HWZ + base) = acc;
        }
    }
}

extern "C" void kernel_launch(void* const* d_in, const int* in_sizes, int n_in,
                              void* d_out, int out_size, void* d_ws, size_t ws_size,
                              hipStream_t stream) {
    const float* gd = (const float*)d_in[0];   // guidance (24,128,128,16) f32
    const float* blur = (const float*)d_in[1]; // blur (20,128,128,16) f32
    float* out = (float*)d_out;                // (20,128,128,16) f32
    float* ws = (float*)d_ws;

    const size_t yz_lds = (size_t)CPGF2 * W * Zd * sizeof(float);  // 80 KB
    // One-time-effect attribute (idempotent, non-stream call: graph-capture safe)
    hipFuncSetAttribute((const void*)prop_yz,
                        hipFuncAttributeMaxDynamicSharedMemorySize, (int)yz_lds);

    prop_x<<<dim3(1024), dim3(256), 0, stream>>>(gd, blur, ws);      // X: blur -> ws
    prop_yz<<<dim3(256), dim3(512), yz_lds, stream>>>(gd, ws, out);  // Y+Z: ws -> out
}